// Round 6
// baseline (379.892 us; speedup 1.0000x reference)
//
#include <hip/hip_runtime.h>
#include <hip/hip_bf16.h>
#include <math.h>

typedef unsigned short u16;
typedef unsigned int   u32;
using short8  = __attribute__((ext_vector_type(8))) short;
using f32x4   = __attribute__((ext_vector_type(4))) float;

static constexpr int NNODE = 50000;
static constexpr int NEDGE = 600000;
static constexpr float EPSC   = 0.1f;
static constexpr float GAMMAC = 0.1f;

static constexpr int NTILE  = (NNODE + 63) / 64;   // 782 row-tiles
static constexpr int NSPLIT = NTILE * 2;           // 1564 col-split GEMM blocks
static constexpr int XDEG   = 160;                 // deg-count role blocks
static constexpr int XW     = 64;                  // weight-prep role blocks

// ---- workspace layout (float-index offsets) ----
static constexpr long long O_DINV   = 0;                   // float 50000
static constexpr long long O_DEGI   = 50000;               // int 50000
static constexpr long long O_GCUR   = 100000;              // int 1 (adjacent: one memset)
static constexpr long long O_ROWPTR = 100004;              // int 50000
static constexpr long long O_CURSOR = 150004;              // int 50000
static constexpr long long O_ECSR   = 200260;              // int2 600000
// bf16 weights needing transposed-access prep (built by xgemm role blocks)
static constexpr long long O_G1TB   = 1400260;             // 16384 bf16
static constexpr long long O_AW1B   = O_G1TB + 8192;       // 16384 bf16
static constexpr long long O_AW2B   = O_AW1B + 8192;       // 4096 bf16
static constexpr long long O_G2TB   = O_AW2B + 2048;       // 4096 bf16
// big buffers
static constexpr long long O_AGGB   = 3450004;             // bf16 6.4M
static constexpr long long O_HB0    = O_AGGB + 3200000;    // bf16 6.4M
static constexpr long long O_HB1    = O_HB0  + 3200000;    // bf16 6.4M
static constexpr long long O_S0     = O_HB1  + 3200000;    // fp8 6.4M
static constexpr long long O_S1     = O_S0   + 1600000;    // fp8 6.4M

__device__ __forceinline__ float bf2f(u16 u) {
    return __uint_as_float(((unsigned)u) << 16);
}
__device__ __forceinline__ u16 f2bf(float f) {
    unsigned u = __float_as_uint(f);
    return (u16)((u + 0x7FFFu + ((u >> 16) & 1u)) >> 16);
}
__device__ __forceinline__ short8 cvt8(const float4 a, const float4 b) {
    short8 t;
    t[0]=(short)f2bf(a.x); t[1]=(short)f2bf(a.y); t[2]=(short)f2bf(a.z); t[3]=(short)f2bf(a.w);
    t[4]=(short)f2bf(b.x); t[5]=(short)f2bf(b.y); t[6]=(short)f2bf(b.z); t[7]=(short)f2bf(b.w);
    return t;
}
__device__ __forceinline__ float ftanh(float x) {
    float x2 = fminf(fmaxf(2.f * x, -30.f), 30.f);
    float e = __expf(x2);
    return (e - 1.f) * __builtin_amdgcn_rcpf(e + 1.f);
}
__device__ __forceinline__ u16 pk_fp8(float a, float b) {
    int pk = __builtin_amdgcn_cvt_pk_fp8_f32(a, b, 0, false);
    return (u16)(pk & 0xffff);
}
__device__ __forceinline__ void acc_fp8x4(float* a, u32 v, float w) {
    a[0] += __builtin_amdgcn_cvt_f32_fp8(v, 0) * w;
    a[1] += __builtin_amdgcn_cvt_f32_fp8(v, 1) * w;
    a[2] += __builtin_amdgcn_cvt_f32_fp8(v, 2) * w;
    a[3] += __builtin_amdgcn_cvt_f32_fp8(v, 3) * w;
}

// ---- CSR build ----
__global__ __launch_bounds__(256) void alloc_kernel(const int* __restrict__ degi,
                                                    float* __restrict__ dinv,
                                                    int* __restrict__ rowptr,
                                                    int* __restrict__ cursor,
                                                    int* __restrict__ gcur) {
    int i = blockIdx.x * 256 + threadIdx.x;
    if (i >= NNODE) return;
    int d = degi[i];
    dinv[i] = rsqrtf(1.0f + (float)d);   // +1 self loop
    int pos = atomicAdd(gcur, d);
    rowptr[i] = pos;
    cursor[i] = pos;
}
__global__ __launch_bounds__(256) void fill_kernel(const int* __restrict__ ei,
                                                   const float* __restrict__ dinv,
                                                   int* __restrict__ cursor,
                                                   int2* __restrict__ ecsr) {
    int e = blockIdx.x * 256 + threadIdx.x;
    if (e >= NEDGE) return;
    int s = ei[e], d = ei[NEDGE + e];
    int pos = atomicAdd(&cursor[d], 1);
    int2 v;
    v.x = s;
    v.y = __float_as_int(dinv[s]);       // dinv[d] hoisted into gather epilogue
    ecsr[pos] = v;
}

// ---- x-GEMM (col-split 64x64 tiles) + deg-count role + weight-prep role ----
__global__ __launch_bounds__(256, 6) void xgemm(
    const float* __restrict__ x, const float* __restrict__ w_hid,
    const float* __restrict__ bias,
    u16* __restrict__ outB, u16* __restrict__ outB8,
    const int* __restrict__ ei, int* __restrict__ degi,
    const float* __restrict__ W_a1, const float* __restrict__ gcn1,
    const float* __restrict__ W_a2, const float* __restrict__ gcn2,
    float* __restrict__ ws)
{
    if (blockIdx.x >= NSPLIT) {
        int rb = blockIdx.x - NSPLIT;
        if (rb < XDEG) {
            for (int e = rb * 256 + threadIdx.x; e < NEDGE; e += XDEG * 256)
                atomicAdd(&degi[ei[NEDGE + e]], 1);
        } else {
            // transpose-access weights -> bf16 (consumed by LATER kernels)
            u16* g1t = (u16*)(ws + O_G1TB);
            u16* aw1 = (u16*)(ws + O_AW1B);
            u16* aw2 = (u16*)(ws + O_AW2B);
            u16* g2t = (u16*)(ws + O_G2TB);
            for (int j0 = (rb - XDEG) * 256 + threadIdx.x; j0 < 40960; j0 += XW * 256) {
                int j = j0;
                if (j < 16384) { int r=j>>7, c=j&127; g1t[j] = f2bf(gcn1[c*128+r]); }
                else { j -= 16384;
                if (j < 16384) { int r=j>>7, c=j&127;
                    aw1[j] = f2bf(W_a1[r*128+c] - W_a1[c*128+r] - (r==c?GAMMAC:0.f)); }
                else { j -= 16384;
                if (j < 4096)  { int r=j>>6, c=j&63;
                    aw2[j] = f2bf(W_a2[r*64+c] - W_a2[c*64+r] - (r==c?GAMMAC:0.f)); }
                else { j -= 4096; int r=j>>6, c=j&63; g2t[j] = f2bf(gcn2[c*64+r]); } } }
            }
        }
        return;
    }

    constexpr int P = 72, CW = 65;
    __shared__ __align__(16) char smem[9216];
    u16*   bl   = (u16*)smem;
    float* accL = (float*)smem;
    const int wave = threadIdx.x >> 6, lane = threadIdx.x & 63;
    const int m = lane & 15, q = lane >> 4;
    const int tile = blockIdx.x >> 1, nh = blockIdx.x & 1;
    const int rowbase = tile * 64 + wave * 16;
    const int row = rowbase + m;
    const bool rok = row < NNODE;
    const short8 z8 = {0,0,0,0,0,0,0,0};

    short8 af[8];
    {
        const float* apf = x + (long long)row * 256;
        #pragma unroll
        for (int k = 0; k < 8; ++k) {
            short8 t = z8;
            if (rok) {
                const float4* p = (const float4*)(apf + (k * 4 + q) * 8);
                t = cvt8(p[0], p[1]);
            }
            af[k] = t;
        }
    }

    f32x4 acc[4];
    #pragma unroll
    for (int j = 0; j < 4; ++j) acc[j] = (f32x4){0.f,0.f,0.f,0.f};

    #pragma unroll
    for (int ch = 0; ch < 4; ++ch) {               // K = 256 in 4 chunks of 64
        if (ch) __syncthreads();
        for (int t = threadIdx.x; t < 512; t += 256) {
            int r = t >> 3, c = t & 7;
            const float4* pw = (const float4*)&w_hid[(long long)(nh*64 + r) * 256 + ch*64 + c*8];
            *(short8*)&bl[r * P + c * 8] = cvt8(pw[0], pw[1]);
        }
        __syncthreads();
        #pragma unroll
        for (int j = 0; j < 4; ++j)
            #pragma unroll
            for (int kk = 0; kk < 2; ++kk) {
                short8 b_ = *(const short8*)&bl[(j*16 + m) * P + kk*32 + q*8];
                acc[j] = __builtin_amdgcn_mfma_f32_16x16x32_bf16(af[ch*2 + kk], b_, acc[j], 0, 0, 0);
            }
    }

    // epilogue: 2-pass LDS transpose (32 rows x 65 f32 = 8320B), leaky + store
    const int hw = lane >> 5;
    const int c0 = (lane & 31) * 2;
    float2 bv = {bias[nh*64 + c0], bias[nh*64 + c0 + 1]};
    #pragma unroll
    for (int p = 0; p < 2; ++p) {
        __syncthreads();
        if ((wave >> 1) == p) {
            int lr = (wave & 1) * 16;
            #pragma unroll
            for (int j = 0; j < 4; ++j)
                #pragma unroll
                for (int r = 0; r < 4; ++r)
                    accL[(lr + q*4 + r) * CW + j*16 + m] = acc[j][r];
        }
        __syncthreads();
        if ((wave >> 1) == p) {
            int lr = (wave & 1) * 16;
            #pragma unroll
            for (int rl8 = 0; rl8 < 8; ++rl8) {
                int rl = hw * 8 + rl8;
                int rowD = rowbase + rl;
                if (rowD >= NNODE) continue;
                float2 v = *(const float2*)&accL[(lr + rl) * CW + c0];
                v.x += bv.x; v.y += bv.y;
                v.x = v.x > 0.f ? v.x : 0.01f * v.x;
                v.y = v.y > 0.f ? v.y : 0.01f * v.y;
                long long o = (long long)rowD * 128 + nh*64 + c0;
                ushort2 ob; ob.x = f2bf(v.x); ob.y = f2bf(v.y);
                *(ushort2*)&outB[o] = ob;
                outB8[o >> 1] = pk_fp8(v.x, v.y);
            }
        }
    }
}

// ---- CSR gather (fp8 in, bf16 out), wave per node, dinv-hoisted ----
template<int HD>
__global__ __launch_bounds__(256) void gather_kernel(
    const int* __restrict__ rowptr, const int* __restrict__ degi,
    const int2* __restrict__ ecsr, const float* __restrict__ dinv,
    const u32* __restrict__ g8, u16* __restrict__ aggB)
{
    int node = (blockIdx.x * 256 + threadIdx.x) >> 6;
    int lane = threadIdx.x & 63;
    if (node >= NNODE) return;
    const int qr = lane >> 4, l4 = lane & 15;
    const int r0 = rowptr[node];
    const int r1 = r0 + degi[node];
    const float dn = dinv[node];
    constexpr int EL = (HD == 128) ? 8 : 4;

    float a[EL];
    #pragma unroll
    for (int i = 0; i < EL; ++i) a[i] = 0.f;
    if (qr == 0) {      // self term: dn * s_node (final *dn gives dn^2)
        if (HD == 128) {
            uint2 gv = ((const uint2*)g8)[(long long)node * 16 + l4];
            acc_fp8x4(a, gv.x, dn);
            acc_fp8x4(a + 4, gv.y, dn);
        } else {
            u32 gv = g8[(long long)node * 16 + l4];
            acc_fp8x4(a, gv, dn);
        }
    }

    for (int base = r0; base < r1; base += 64) {
        int idx = base + lane;
        int cs = 0; float cw = 0.f;
        if (idx < r1) { int2 ev = ecsr[idx]; cs = ev.x; cw = __int_as_float(ev.y); }
        int cnt = min(64, r1 - base);
        for (int j = 0; j < cnt; j += 16) {        // 4 independent loads in flight
            #pragma unroll
            for (int u = 0; u < 4; ++u) {
                int jj = j + u * 4 + qr;           // lanes past cnt carry cw=0
                int   s = __shfl(cs, jj);
                float w = __shfl(cw, jj);
                if (HD == 128) {
                    uint2 gv = ((const uint2*)g8)[(long long)s * 16 + l4];
                    acc_fp8x4(a, gv.x, w);
                    acc_fp8x4(a + 4, gv.y, w);
                } else {
                    u32 gv = g8[(long long)s * 16 + l4];
                    acc_fp8x4(a, gv, w);
                }
            }
        }
    }

    #pragma unroll
    for (int i = 0; i < EL; ++i) {
        a[i] += __shfl_xor(a[i], 16);
        a[i] += __shfl_xor(a[i], 32);
    }
    if (HD == 128) {
        float v0 = (qr == 0) ? a[0] : (qr == 1) ? a[2] : (qr == 2) ? a[4] : a[6];
        float v1 = (qr == 0) ? a[1] : (qr == 1) ? a[3] : (qr == 2) ? a[5] : a[7];
        v0 *= dn; v1 *= dn;
        long long o = (long long)node * 128 + l4 * 8 + qr * 2;
        ushort2 ob; ob.x = f2bf(v0); ob.y = f2bf(v1);
        *(ushort2*)&aggB[o] = ob;
    } else {
        float v = (qr == 0) ? a[0] : (qr == 1) ? a[1] : (qr == 2) ? a[2] : a[3];
        aggB[(long long)node * 64 + l4 * 4 + qr] = f2bf(v * dn);
    }
}

// ---- conv step (col-split 64x64): acc = h@aW^T + (Ah)@G, epi h+eps*tanh ----
__global__ __launch_bounds__(256, 6) void convs(
    const u16* __restrict__ hA, const u16* __restrict__ gA,
    const u16* __restrict__ BtW, const u16* __restrict__ BtG,
    const float* __restrict__ bias,
    u16* __restrict__ outB, u16* __restrict__ outB8)
{
    constexpr int K = 128, P = 72, CW = 65;
    __shared__ __align__(16) char smem[9216];
    u16*   bl   = (u16*)smem;
    float* accL = (float*)smem;
    const int wave = threadIdx.x >> 6, lane = threadIdx.x & 63;
    const int m = lane & 15, q = lane >> 4;
    const int tile = blockIdx.x >> 1, nh = blockIdx.x & 1;
    const int rowbase = tile * 64 + wave * 16;
    const int row = rowbase + m;
    const bool rok = row < NNODE;
    const short8 z8 = {0,0,0,0,0,0,0,0};

    short8 af1[4], af2[4];
    {
        const short8* ap1 = (const short8*)(hA + (long long)row * K);
        const short8* ap2 = (const short8*)(gA + (long long)row * K);
        #pragma unroll
        for (int k = 0; k < 4; ++k) {
            af1[k] = rok ? ap1[k * 4 + q] : z8;
            af2[k] = rok ? ap2[k * 4 + q] : z8;
        }
    }

    f32x4 acc[4];
    #pragma unroll
    for (int j = 0; j < 4; ++j) acc[j] = (f32x4){0.f,0.f,0.f,0.f};

    #pragma unroll
    for (int ph = 0; ph < 4; ++ph) {               // {W,G} x {K-chunk 0,1}
        const int pass = ph >> 1, ch = ph & 1;
        const u16* Bsrc = pass ? BtG : BtW;
        if (ph) __syncthreads();
        for (int t = threadIdx.x; t < 512; t += 256) {
            int r = t >> 3, c = t & 7;
            *(short8*)&bl[r * P + c * 8] =
                *(const short8*)&Bsrc[(long long)(nh*64 + r) * K + ch*64 + c*8];
        }
        __syncthreads();
        #pragma unroll
        for (int j = 0; j < 4; ++j)
            #pragma unroll
            for (int kk = 0; kk < 2; ++kk) {
                short8 b_ = *(const short8*)&bl[(j*16 + m) * P + kk*32 + q*8];
                acc[j] = __builtin_amdgcn_mfma_f32_16x16x32_bf16(
                    pass ? af2[2*ch + kk] : af1[2*ch + kk], b_, acc[j], 0, 0, 0);
            }
    }

    const int hw = lane >> 5;
    const int c0 = (lane & 31) * 2;
    float2 bv = {bias[nh*64 + c0], bias[nh*64 + c0 + 1]};
    #pragma unroll
    for (int p = 0; p < 2; ++p) {
        __syncthreads();
        if ((wave >> 1) == p) {
            int lr = (wave & 1) * 16;
            #pragma unroll
            for (int j = 0; j < 4; ++j)
                #pragma unroll
                for (int r = 0; r < 4; ++r)
                    accL[(lr + q*4 + r) * CW + j*16 + m] = acc[j][r];
        }
        __syncthreads();
        if ((wave >> 1) == p) {
            int lr = (wave & 1) * 16;
            #pragma unroll
            for (int rl8 = 0; rl8 < 8; ++rl8) {
                int rl = hw * 8 + rl8;
                int rowD = rowbase + rl;
                if (rowD >= NNODE) continue;
                float2 v = *(const float2*)&accL[(lr + rl) * CW + c0];
                long long o = (long long)rowD * 128 + nh*64 + c0;
                ushort2 hh = *(const ushort2*)&hA[o];
                float n0 = bf2f(hh.x) + EPSC * ftanh(v.x + bv.x);
                float n1 = bf2f(hh.y) + EPSC * ftanh(v.y + bv.y);
                ushort2 ob; ob.x = f2bf(n0); ob.y = f2bf(n1);
                *(ushort2*)&outB[o] = ob;
                outB8[o >> 1] = pk_fp8(n0, n1);
            }
        }
    }
}

// ---- conv step iter3 (full-width) + fused h2 = leaky(leaky(h_new)@w2^T+b2) ----
__global__ __launch_bounds__(256, 4) void convt(
    const u16* __restrict__ hA, const u16* __restrict__ gA,
    const u16* __restrict__ BtW, const u16* __restrict__ BtG,
    const float* __restrict__ bias,
    u16* __restrict__ outB, u16* __restrict__ outB8,
    const float* __restrict__ w2f, const float* __restrict__ b2)
{
    constexpr int K = 128, P = 72, CW = 129, PH = 136;
    __shared__ __align__(16) char smem[18432];
    u16*   bl   = (u16*)smem;
    float* accL = (float*)smem;
    const int wave = threadIdx.x >> 6, lane = threadIdx.x & 63;
    const int m = lane & 15, q = lane >> 4;
    const int rowbase = blockIdx.x * 64 + wave * 16;
    const int row = rowbase + m;
    const bool rok = row < NNODE;
    const short8 z8 = {0,0,0,0,0,0,0,0};

    short8 af1[4], af2[4];
    {
        const short8* ap1 = (const short8*)(hA + (long long)row * K);
        const short8* ap2 = (const short8*)(gA + (long long)row * K);
        #pragma unroll
        for (int k = 0; k < 4; ++k) {
            af1[k] = rok ? ap1[k * 4 + q] : z8;
            af2[k] = rok ? ap2[k * 4 + q] : z8;
        }
    }

    f32x4 acc[8];
    #pragma unroll
    for (int j = 0; j < 8; ++j) acc[j] = (f32x4){0.f,0.f,0.f,0.f};

    #pragma unroll
    for (int ph = 0; ph < 4; ++ph) {               // {W,G} x {K-chunk 0,1}, full 128 rows
        const int pass = ph >> 1, ch = ph & 1;
        const u16* Bsrc = pass ? BtG : BtW;
        if (ph) __syncthreads();
        for (int t = threadIdx.x; t < 1024; t += 256) {
            int r = t >> 3, c = t & 7;
            *(short8*)&bl[r * P + c * 8] =
                *(const short8*)&Bsrc[(long long)r * K + ch*64 + c*8];
        }
        __syncthreads();
        #pragma unroll
        for (int j = 0; j < 8; ++j)
            #pragma unroll
            for (int kk = 0; kk < 2; ++kk) {
                short8 b_ = *(const short8*)&bl[(j*16 + m) * P + kk*32 + q*8];
                acc[j] = __builtin_amdgcn_mfma_f32_16x16x32_bf16(
                    pass ? af2[2*ch + kk] : af1[2*ch + kk], b_, acc[j], 0, 0, 0);
            }
    }

    // h_new = h + eps*tanh(acc+b), leaky -> hv regs (2-pass accL, 32x129 f32)
    const int c0 = lane * 2;
    u32 hv[16];
    {
        float2 bv = {bias[c0], bias[c0 + 1]};
        #pragma unroll
        for (int p = 0; p < 2; ++p) {
            __syncthreads();
            if ((wave >> 1) == p) {
                int lr = (wave & 1) * 16;
                #pragma unroll
                for (int j = 0; j < 8; ++j)
                    #pragma unroll
                    for (int r = 0; r < 4; ++r)
                        accL[(lr + q*4 + r) * CW + j*16 + m] = acc[j][r];
            }
            __syncthreads();
            if ((wave >> 1) == p) {
                int lr = (wave & 1) * 16;
                #pragma unroll
                for (int rl = 0; rl < 16; ++rl) {
                    int rowD = rowbase + rl;
                    float n0 = 0.f, n1 = 0.f;
                    if (rowD < NNODE) {
                        float2 v = *(const float2*)&accL[(lr + rl) * CW + c0];
                        long long o = (long long)rowD * K + c0;
                        ushort2 hh = *(const ushort2*)&hA[o];
                        n0 = bf2f(hh.x) + EPSC * ftanh(v.x + bv.x);
                        n1 = bf2f(hh.y) + EPSC * ftanh(v.y + bv.y);
                        n0 = n0 > 0.f ? n0 : 0.01f * n0;
                        n1 = n1 > 0.f ? n1 : 0.01f * n1;
                    }
                    hv[rl] = (u32)f2bf(n0) | ((u32)f2bf(n1) << 16);
                }
            }
        }
    }

    // h_new tile -> LDS [64][136] bf16, read A-frags
    __syncthreads();
    #pragma unroll
    for (int rl = 0; rl < 16; ++rl)
        *(u32*)&bl[(wave*16 + rl) * PH + c0] = hv[rl];
    __syncthreads();
    short8 af3[4];
    #pragma unroll
    for (int k = 0; k < 4; ++k)
        af3[k] = *(const short8*)&bl[(wave*16 + m) * PH + k*32 + q*8];

    // h2 GEMM: w2 [64][128] f32 on-the-fly, 2 K-chunks
    f32x4 acc2[4];
    #pragma unroll
    for (int j = 0; j < 4; ++j) acc2[j] = (f32x4){0.f,0.f,0.f,0.f};
    #pragma unroll
    for (int ch = 0; ch < 2; ++ch) {
        __syncthreads();
        for (int t = threadIdx.x; t < 512; t += 256) {
            int r = t >> 3, c = t & 7;
            const float4* pw = (const float4*)&w2f[(long long)r * K + ch*64 + c*8];
            *(short8*)&bl[r * P + c * 8] = cvt8(pw[0], pw[1]);
        }
        __syncthreads();
        #pragma unroll
        for (int j = 0; j < 4; ++j)
            #pragma unroll
            for (int kk = 0; kk < 2; ++kk) {
                short8 b_ = *(const short8*)&bl[(j*16 + m) * P + kk*32 + q*8];
                acc2[j] = __builtin_amdgcn_mfma_f32_16x16x32_bf16(af3[2*ch + kk], b_, acc2[j], 0, 0, 0);
            }
    }

    // h2 epilogue (2-pass, 32x65 f32), leaky, store
    constexpr int CW2 = 65;
    const int hw = lane >> 5;
    const int c2 = (lane & 31) * 2;
    float2 bv2 = {b2[c2], b2[c2 + 1]};
    #pragma unroll
    for (int p = 0; p < 2; ++p) {
        __syncthreads();
        if ((wave >> 1) == p) {
            int lr = (wave & 1) * 16;
            #pragma unroll
            for (int j = 0; j < 4; ++j)
                #pragma unroll
                for (int r = 0; r < 4; ++r)
                    accL[(lr + q*4 + r) * CW2 + j*16 + m] = acc2[j][r];
        }
        __syncthreads();
        if ((wave >> 1) == p) {
            int lr = (wave & 1) * 16;
            #pragma unroll
            for (int rl8 = 0; rl8 < 8; ++rl8) {
                int rl = hw * 8 + rl8;
                int rowD = rowbase + rl;
                if (rowD >= NNODE) continue;
                float2 v = *(const float2*)&accL[(lr + rl) * CW2 + c2];
                v.x += bv2.x; v.y += bv2.y;
                v.x = v.x > 0.f ? v.x : 0.01f * v.x;
                v.y = v.y > 0.f ? v.y : 0.01f * v.y;
                long long o = (long long)rowD * 64 + c2;
                ushort2 ob; ob.x = f2bf(v.x); ob.y = f2bf(v.y);
                *(ushort2*)&outB[o] = ob;
                outB8[o >> 1] = pk_fp8(v.x, v.y);
            }
        }
    }
}

// ---- fused conv2 + FC + log_softmax ----
__global__ __launch_bounds__(256, 4) void conv2fc(
    const u16* __restrict__ hA,      // h2 [M,64] bf16
    const u16* __restrict__ gA,      // Ah2 [M,64] bf16
    const u16* __restrict__ BtW, const u16* __restrict__ BtG,
    const float* __restrict__ bias,
    const float* __restrict__ wfc, const float* __restrict__ bfc,
    float* __restrict__ outF)
{
    constexpr int K = 64, NT = 4, KS = 2, P = 72, CW = 65;
    constexpr int R1 = 64 * CW * 4;    // 16640
    __shared__ __align__(16) char smem[R1 + 64 * P * 2];
    u16*   bl   = (u16*)smem;
    float* accL = (float*)smem;
    u16*   aggT = (u16*)(smem + R1);
    const int wave = threadIdx.x >> 6, lane = threadIdx.x & 63;
    const int m = lane & 15, q = lane >> 4;
    const int rowbase = blockIdx.x * 64 + wave * 16;
    const int row = rowbase + m;
    const bool rok = row < NNODE;
    const short8 z8 = {0,0,0,0,0,0,0,0};

    short8 af1[KS], af2[KS];
    {
        const short8* ap1 = (const short8*)(hA + (long long)row * K);
        const short8* ap2 = (const short8*)(gA + (long long)row * K);
        #pragma unroll
        for (int k = 0; k < KS; ++k) {
            af1[k] = rok ? ap1[k * 4 + q] : z8;
            af2[k] = rok ? ap2[k * 4 + q] : z8;
        }
    }

    f32x4 acc[NT];
    #pragma unroll
    for (int j = 0; j < NT; ++j) acc[j] = (f32x4){0.f,0.f,0.f,0.f};

    #pragma unroll
    for (int pass = 0; pass < 2; ++pass) {
        const u16* Bcur = pass ? BtG : BtW;
        if (pass) __syncthreads();
        for (int t = threadIdx.x; t < 512; t += 256) {
            int r = t >> 3, c = t & 7;
            *(short8*)&bl[r * P + c * 8] = *(const short8*)&Bcur[(long long)r * K + c * 8];
        }
        __syncthreads();
        #pragma unroll
        for (int j = 0; j < NT; ++j)
            #pragma unroll
            for (int k = 0; k < KS; ++k) {
                short8 b_ = *(const short8*)&bl[(j*16 + m) * P + k*32 + q*8];
                acc[j] = __builtin_amdgcn_mfma_f32_16x16x32_bf16(
                    pass ? af2[k] : af1[k], b_, acc[j], 0, 0, 0);
            }
    }

    __syncthreads();
    #pragma unroll
    for (int j = 0; j < NT; ++j)
        #pragma unroll
        for (int r = 0; r < 4; ++r)
            accL[(wave*16 + q*4 + r) * CW + j*16 + m] = acc[j][r];
    __syncthreads();

    // h2n = h2 + eps*tanh(acc + b_a2) -> aggT tile
    {
        const int c0 = lane * 2;
        if (c0 < 64) {
            float2 bv = {bias[c0], bias[c0 + 1]};
            #pragma unroll
            for (int rl = 0; rl < 16; ++rl) {
                int rowD = rowbase + rl;
                float n0 = 0.f, n1 = 0.f;
                if (rowD < NNODE) {
                    float2 v = *(const float2*)&accL[(wave*16 + rl) * CW + c0];
                    long long o = (long long)rowD * 64 + c0;
                    ushort2 hh = *(const ushort2*)&hA[o];
                    n0 = bf2f(hh.x) + EPSC * ftanh(v.x + bv.x);
                    n1 = bf2f(hh.y) + EPSC * ftanh(v.y + bv.y);
                }
                ushort2 ob; ob.x = f2bf(n0); ob.y = f2bf(n1);
                *(ushort2*)&aggT[(wave*16 + rl) * P + c0] = ob;
            }
        }
    }
    __syncthreads();

    short8 af4[KS];
    #pragma unroll
    for (int k = 0; k < KS; ++k)
        af4[k] = *(const short8*)&aggT[(wave*16 + m) * P + k*32 + q*8];

    // stage wfc [40,64] f32 -> bf16 on the fly, zero-pad to 48 rows
    for (int t = threadIdx.x; t < 384; t += 256) {
        int r = t >> 3, c = t & 7;
        short8 v = z8;
        if (r < 40) {
            const float4* pw = (const float4*)&wfc[(long long)r * K + c * 8];
            v = cvt8(pw[0], pw[1]);
        }
        *(short8*)&bl[r * P + c * 8] = v;
    }
    __syncthreads();

    f32x4 acc3[3];
    #pragma unroll
    for (int j = 0; j < 3; ++j) acc3[j] = (f32x4){0.f,0.f,0.f,0.f};
    #pragma unroll
    for (int j = 0; j < 3; ++j)
        #pragma unroll
        for (int k = 0; k < KS; ++k) {
            short8 b_ = *(const short8*)&bl[(j*16 + m) * P + k*32 + q*8];
            acc3[j] = __builtin_amdgcn_mfma_f32_16x16x32_bf16(af4[k], b_, acc3[j], 0, 0, 0);
        }

    __syncthreads();
    constexpr int CW3 = 49;
    #pragma unroll
    for (int j = 0; j < 3; ++j)
        #pragma unroll
        for (int r = 0; r < 4; ++r)
            accL[(wave*16 + q*4 + r) * CW3 + j*16 + m] = acc3[j][r];
    __syncthreads();

    float mrow = 0.f, lrow = 0.f;
    if (lane < 16) {
        const float* rp = &accL[(wave*16 + lane) * CW3];
        float mx = -1e30f;
        for (int c = 0; c < 40; ++c) mx = fmaxf(mx, rp[c] + bfc[c]);
        float s = 0.f;
        for (int c = 0; c < 40; ++c) s += expf(rp[c] + bfc[c] - mx);
        mrow = mx; lrow = logf(s);
    }
    for (int rl = 0; rl < 16; ++rl) {
        float mm = __shfl(mrow, rl);
        float ll = __shfl(lrow, rl);
        int rowD = rowbase + rl;
        if (rowD < NNODE && lane < 40) {
            float v = accL[(wave*16 + rl) * CW3 + lane] + bfc[lane];
            outF[(long long)rowD * 40 + lane] = v - mm - ll;
        }
    }
}

extern "C" void kernel_launch(void* const* d_in, const int* in_sizes, int n_in,
                              void* d_out, int out_size, void* d_ws, size_t ws_size,
                              hipStream_t stream) {
    const float* x     = (const float*)d_in[0];
    const int*   ei    = (const int*)d_in[1];
    const float* w_hid = (const float*)d_in[2];
    const float* b_hid = (const float*)d_in[3];
    const float* W_a1  = (const float*)d_in[4];
    const float* gcn1  = (const float*)d_in[5];
    const float* b_a1  = (const float*)d_in[6];
    const float* w2    = (const float*)d_in[7];
    const float* b2    = (const float*)d_in[8];
    const float* W_a2  = (const float*)d_in[9];
    const float* gcn2  = (const float*)d_in[10];
    const float* b_a2  = (const float*)d_in[11];
    const float* wfc   = (const float*)d_in[12];
    const float* bfc   = (const float*)d_in[13];
    float* ws = (float*)d_ws;
    float* out = (float*)d_out;

    float* dinv   = ws + O_DINV;
    int*   degi   = (int*)(ws + O_DEGI);
    int*   gcur   = (int*)(ws + O_GCUR);
    int*   rowptr = (int*)(ws + O_ROWPTR);
    int*   cursor = (int*)(ws + O_CURSOR);
    int2*  ecsr   = (int2*)(ws + O_ECSR);
    u16* g1tB = (u16*)(ws + O_G1TB);
    u16* aw1B = (u16*)(ws + O_AW1B);
    u16* aw2B = (u16*)(ws + O_AW2B);
    u16* g2tB = (u16*)(ws + O_G2TB);
    u16* aggB = (u16*)(ws + O_AGGB);
    u16* hB0  = (u16*)(ws + O_HB0);
    u16* hB1  = (u16*)(ws + O_HB1);
    u16* s0   = (u16*)(ws + O_S0);
    u16* s1   = (u16*)(ws + O_S1);

    // zero degi (50000 ints) + gcur (adjacent) in one async fill
    hipMemsetAsync((char*)d_ws + (size_t)O_DEGI * 4, 0, (NNODE + 1) * 4, stream);

    // x-GEMM (col-split) + concurrent deg-count + weight-prep roles
    xgemm<<<NSPLIT + XDEG + XW, 256, 0, stream>>>(
        x, w_hid, b_hid, hB0, s0, ei, degi, W_a1, gcn1, W_a2, gcn2, ws);

    const int nNodeB = (NNODE + 255) / 256;
    alloc_kernel<<<nNodeB, 256, 0, stream>>>(degi, dinv, rowptr, cursor, gcur);
    fill_kernel<<<(NEDGE + 255) / 256, 256, 0, stream>>>(ei, dinv, cursor, ecsr);

    const int gatherBlocks = (NNODE * 64 + 255) / 256;   // 12500

    // conv1 iter1
    gather_kernel<128><<<gatherBlocks, 256, 0, stream>>>(
        rowptr, degi, ecsr, dinv, (const u32*)s0, aggB);
    convs<<<NSPLIT, 256, 0, stream>>>(hB0, aggB, aw1B, g1tB, b_a1, hB1, s1);
    // conv1 iter2
    gather_kernel<128><<<gatherBlocks, 256, 0, stream>>>(
        rowptr, degi, ecsr, dinv, (const u32*)s1, aggB);
    convs<<<NSPLIT, 256, 0, stream>>>(hB1, aggB, aw1B, g1tB, b_a1, hB0, s0);
    // conv1 iter3 + fused h2 GEMM (full-width)
    gather_kernel<128><<<gatherBlocks, 256, 0, stream>>>(
        rowptr, degi, ecsr, dinv, (const u32*)s0, aggB);
    convt<<<NTILE, 256, 0, stream>>>(hB0, aggB, aw1B, g1tB, b_a1, hB1, s1, w2, b2);

    // conv2 + fc + log_softmax
    gather_kernel<64><<<gatherBlocks, 256, 0, stream>>>(
        rowptr, degi, ecsr, dinv, (const u32*)s1, aggB);
    conv2fc<<<NTILE, 256, 0, stream>>>(hB1, aggB, aw2B, g2tB, b_a2, wfc, bfc, out);
}

// Round 7
// 372.976 us; speedup vs baseline: 1.0185x; 1.0185x over previous
//
#include <hip/hip_runtime.h>
#include <hip/hip_bf16.h>
#include <math.h>

typedef unsigned short u16;
typedef unsigned int   u32;
using short8  = __attribute__((ext_vector_type(8))) short;
using f32x4   = __attribute__((ext_vector_type(4))) float;

static constexpr int NNODE = 50000;
static constexpr int NEDGE = 600000;
static constexpr float EPSC   = 0.1f;
static constexpr float GAMMAC = 0.1f;

static constexpr int NTILE = (NNODE + 63) / 64;    // 782 64-row tiles (convt/conv2fc)
static constexpr int NT32  = (NNODE + 31) / 32;    // 1563 32-row tiles (xgemm/convs)
static constexpr int XDEG  = 160;                  // deg-count role blocks
static constexpr int XW    = 64;                   // weight-prep role blocks

// ---- workspace layout (float-index offsets) ----
static constexpr long long O_DINV   = 0;                   // float 50000
static constexpr long long O_DEGI   = 50000;               // int 50000
static constexpr long long O_GCUR   = 100000;              // int 1 (adjacent: one memset)
static constexpr long long O_ROWPTR = 100004;              // int 50000
static constexpr long long O_CURSOR = 150004;              // int 50000
static constexpr long long O_ECSR   = 200260;              // int2 600000
// bf16 weights needing transposed-access prep (built by xgemm role blocks)
static constexpr long long O_G1TB   = 1400260;             // 16384 bf16
static constexpr long long O_AW1B   = O_G1TB + 8192;       // 16384 bf16
static constexpr long long O_AW2B   = O_AW1B + 8192;       // 4096 bf16
static constexpr long long O_G2TB   = O_AW2B + 2048;       // 4096 bf16
// big buffers
static constexpr long long O_AGGB   = 3450004;             // bf16 6.4M
static constexpr long long O_HB0    = O_AGGB + 3200000;    // bf16 6.4M
static constexpr long long O_HB1    = O_HB0  + 3200000;    // bf16 6.4M
static constexpr long long O_S0     = O_HB1  + 3200000;    // fp8 6.4M
static constexpr long long O_S1     = O_S0   + 1600000;    // fp8 6.4M

__device__ __forceinline__ float bf2f(u16 u) {
    return __uint_as_float(((unsigned)u) << 16);
}
__device__ __forceinline__ u16 f2bf(float f) {
    unsigned u = __float_as_uint(f);
    return (u16)((u + 0x7FFFu + ((u >> 16) & 1u)) >> 16);
}
__device__ __forceinline__ short8 cvt8(const float4 a, const float4 b) {
    short8 t;
    t[0]=(short)f2bf(a.x); t[1]=(short)f2bf(a.y); t[2]=(short)f2bf(a.z); t[3]=(short)f2bf(a.w);
    t[4]=(short)f2bf(b.x); t[5]=(short)f2bf(b.y); t[6]=(short)f2bf(b.z); t[7]=(short)f2bf(b.w);
    return t;
}
__device__ __forceinline__ float ftanh(float x) {
    float x2 = fminf(fmaxf(2.f * x, -30.f), 30.f);
    float e = __expf(x2);
    return (e - 1.f) * __builtin_amdgcn_rcpf(e + 1.f);
}
__device__ __forceinline__ u16 pk_fp8(float a, float b) {
    int pk = __builtin_amdgcn_cvt_pk_fp8_f32(a, b, 0, false);
    return (u16)(pk & 0xffff);
}
__device__ __forceinline__ void acc_fp8x4(float* a, u32 v, float w) {
    a[0] += __builtin_amdgcn_cvt_f32_fp8(v, 0) * w;
    a[1] += __builtin_amdgcn_cvt_f32_fp8(v, 1) * w;
    a[2] += __builtin_amdgcn_cvt_f32_fp8(v, 2) * w;
    a[3] += __builtin_amdgcn_cvt_f32_fp8(v, 3) * w;
}

// ---- CSR build ----
__global__ __launch_bounds__(256) void alloc_kernel(const int* __restrict__ degi,
                                                    float* __restrict__ dinv,
                                                    int* __restrict__ rowptr,
                                                    int* __restrict__ cursor,
                                                    int* __restrict__ gcur) {
    int i = blockIdx.x * 256 + threadIdx.x;
    if (i >= NNODE) return;
    int d = degi[i];
    dinv[i] = rsqrtf(1.0f + (float)d);   // +1 self loop
    int pos = atomicAdd(gcur, d);
    rowptr[i] = pos;
    cursor[i] = pos;
}
__global__ __launch_bounds__(256) void fill_kernel(const int* __restrict__ ei,
                                                   const float* __restrict__ dinv,
                                                   int* __restrict__ cursor,
                                                   int2* __restrict__ ecsr) {
    int e = blockIdx.x * 256 + threadIdx.x;
    if (e >= NEDGE) return;
    int s = ei[e], d = ei[NEDGE + e];
    int pos = atomicAdd(&cursor[d], 1);
    int2 v;
    v.x = s;
    v.y = __float_as_int(dinv[s]);       // dinv[d] hoisted into gather epilogue
    ecsr[pos] = v;
}

// ---- x-GEMM (32-row blocks, per-wave 16x64 tiles) + deg-count + weight-prep ----
__global__ __launch_bounds__(256, 6) void xgemm(
    const float* __restrict__ x, const float* __restrict__ w_hid,
    const float* __restrict__ bias,
    u16* __restrict__ outB, u16* __restrict__ outB8,
    const int* __restrict__ ei, int* __restrict__ degi,
    const float* __restrict__ W_a1, const float* __restrict__ gcn1,
    const float* __restrict__ W_a2, const float* __restrict__ gcn2,
    float* __restrict__ ws)
{
    if (blockIdx.x >= NT32) {
        int rb = blockIdx.x - NT32;
        if (rb < XDEG) {
            for (int e = rb * 256 + threadIdx.x; e < NEDGE; e += XDEG * 256)
                atomicAdd(&degi[ei[NEDGE + e]], 1);
        } else {
            // transpose-access weights -> bf16 (consumed by LATER kernels only)
            u16* g1t = (u16*)(ws + O_G1TB);
            u16* aw1 = (u16*)(ws + O_AW1B);
            u16* aw2 = (u16*)(ws + O_AW2B);
            u16* g2t = (u16*)(ws + O_G2TB);
            for (int j0 = (rb - XDEG) * 256 + threadIdx.x; j0 < 40960; j0 += XW * 256) {
                int j = j0;
                if (j < 16384) { int r=j>>7, c=j&127; g1t[j] = f2bf(gcn1[c*128+r]); }
                else { j -= 16384;
                if (j < 16384) { int r=j>>7, c=j&127;
                    aw1[j] = f2bf(W_a1[r*128+c] - W_a1[c*128+r] - (r==c?GAMMAC:0.f)); }
                else { j -= 16384;
                if (j < 4096)  { int r=j>>6, c=j&63;
                    aw2[j] = f2bf(W_a2[r*64+c] - W_a2[c*64+r] - (r==c?GAMMAC:0.f)); }
                else { j -= 4096; int r=j>>6, c=j&63; g2t[j] = f2bf(gcn2[c*64+r]); } } }
            }
        }
        return;
    }

    constexpr int P = 72;
    __shared__ __align__(16) char smem[18432];   // B-tile [128][72] bf16 / per-wave accL
    u16* bl = (u16*)smem;
    const int wave = threadIdx.x >> 6, lane = threadIdx.x & 63;
    const int m = lane & 15, q = lane >> 4;
    const int nh = wave >> 1;                    // col-half (0/1)
    const int rowbase = blockIdx.x * 32 + (wave & 1) * 16;
    const int row = rowbase + m;
    const bool rok = row < NNODE;
    const short8 z8 = {0,0,0,0,0,0,0,0};

    short8 af[8];                                // full K=256 of this row
    {
        const float* apf = x + (long long)row * 256;
        #pragma unroll
        for (int k = 0; k < 8; ++k) {
            short8 t = z8;
            if (rok) {
                const float4* p = (const float4*)(apf + (k * 4 + q) * 8);
                t = cvt8(p[0], p[1]);
            }
            af[k] = t;
        }
    }

    f32x4 acc[4];
    #pragma unroll
    for (int j = 0; j < 4; ++j) acc[j] = (f32x4){0.f,0.f,0.f,0.f};

    #pragma unroll
    for (int ch = 0; ch < 4; ++ch) {             // K=256 in 4 chunks of 64
        if (ch) __syncthreads();
        for (int t = threadIdx.x; t < 1024; t += 256) {    // 128 rows x 64 cols bf16
            int r = t >> 3, c = t & 7;
            const float4* pw = (const float4*)&w_hid[(long long)r * 256 + ch*64 + c*8];
            *(short8*)&bl[r * P + c * 8] = cvt8(pw[0], pw[1]);
        }
        __syncthreads();
        #pragma unroll
        for (int j = 0; j < 4; ++j)
            #pragma unroll
            for (int kk = 0; kk < 2; ++kk) {
                short8 b_ = *(const short8*)&bl[(nh*64 + j*16 + m) * P + kk*32 + q*8];
                acc[j] = __builtin_amdgcn_mfma_f32_16x16x32_bf16(af[ch*2 + kk], b_, acc[j], 0, 0, 0);
            }
    }

    // per-wave 16x64 epilogue: in-wave LDS transpose (no cross-wave barrier after this sync)
    __syncthreads();                             // all MFMA reads of bl done
    float* accW = (float*)smem + wave * 16 * 65;
    #pragma unroll
    for (int j = 0; j < 4; ++j)
        #pragma unroll
        for (int r = 0; r < 4; ++r)
            accW[(q*4 + r) * 65 + j*16 + m] = acc[j][r];

    const int hw = lane >> 5;
    const int c0 = (lane & 31) * 2;
    float2 bv = {bias[nh*64 + c0], bias[nh*64 + c0 + 1]};
    #pragma unroll
    for (int rl8 = 0; rl8 < 8; ++rl8) {
        int rl = hw * 8 + rl8;
        int rowD = rowbase + rl;
        if (rowD >= NNODE) continue;
        float2 v = *(const float2*)&accW[rl * 65 + c0];
        v.x += bv.x; v.y += bv.y;
        v.x = v.x > 0.f ? v.x : 0.01f * v.x;
        v.y = v.y > 0.f ? v.y : 0.01f * v.y;
        long long o = (long long)rowD * 128 + nh*64 + c0;
        ushort2 ob; ob.x = f2bf(v.x); ob.y = f2bf(v.y);
        *(ushort2*)&outB[o] = ob;
        outB8[o >> 1] = pk_fp8(v.x, v.y);
    }
}

// ---- CSR gather (fp8 in, bf16 out), wave per node, dinv-hoisted ----
template<int HD>
__global__ __launch_bounds__(256) void gather_kernel(
    const int* __restrict__ rowptr, const int* __restrict__ degi,
    const int2* __restrict__ ecsr, const float* __restrict__ dinv,
    const u32* __restrict__ g8, u16* __restrict__ aggB)
{
    int node = (blockIdx.x * 256 + threadIdx.x) >> 6;
    int lane = threadIdx.x & 63;
    if (node >= NNODE) return;
    const int qr = lane >> 4, l4 = lane & 15;
    const int r0 = rowptr[node];
    const int r1 = r0 + degi[node];
    const float dn = dinv[node];
    constexpr int EL = (HD == 128) ? 8 : 4;

    float a[EL];
    #pragma unroll
    for (int i = 0; i < EL; ++i) a[i] = 0.f;
    if (qr == 0) {      // self term: dn * s_node (final *dn gives dn^2)
        if (HD == 128) {
            uint2 gv = ((const uint2*)g8)[(long long)node * 16 + l4];
            acc_fp8x4(a, gv.x, dn);
            acc_fp8x4(a + 4, gv.y, dn);
        } else {
            u32 gv = g8[(long long)node * 16 + l4];
            acc_fp8x4(a, gv, dn);
        }
    }

    for (int base = r0; base < r1; base += 64) {
        int idx = base + lane;
        int cs = 0; float cw = 0.f;
        if (idx < r1) { int2 ev = ecsr[idx]; cs = ev.x; cw = __int_as_float(ev.y); }
        int cnt = min(64, r1 - base);
        for (int j = 0; j < cnt; j += 16) {        // 4 independent loads in flight
            #pragma unroll
            for (int u = 0; u < 4; ++u) {
                int jj = j + u * 4 + qr;           // lanes past cnt carry cw=0
                int   s = __shfl(cs, jj);
                float w = __shfl(cw, jj);
                if (HD == 128) {
                    uint2 gv = ((const uint2*)g8)[(long long)s * 16 + l4];
                    acc_fp8x4(a, gv.x, w);
                    acc_fp8x4(a + 4, gv.y, w);
                } else {
                    u32 gv = g8[(long long)s * 16 + l4];
                    acc_fp8x4(a, gv, w);
                }
            }
        }
    }

    #pragma unroll
    for (int i = 0; i < EL; ++i) {
        a[i] += __shfl_xor(a[i], 16);
        a[i] += __shfl_xor(a[i], 32);
    }
    if (HD == 128) {
        float v0 = (qr == 0) ? a[0] : (qr == 1) ? a[2] : (qr == 2) ? a[4] : a[6];
        float v1 = (qr == 0) ? a[1] : (qr == 1) ? a[3] : (qr == 2) ? a[5] : a[7];
        v0 *= dn; v1 *= dn;
        long long o = (long long)node * 128 + l4 * 8 + qr * 2;
        ushort2 ob; ob.x = f2bf(v0); ob.y = f2bf(v1);
        *(ushort2*)&aggB[o] = ob;
    } else {
        float v = (qr == 0) ? a[0] : (qr == 1) ? a[1] : (qr == 2) ? a[2] : a[3];
        aggB[(long long)node * 64 + l4 * 4 + qr] = f2bf(v * dn);
    }
}

// ---- conv step (32-row blocks, per-wave 16x64): acc = h@aW^T + (Ah)@G ----
__global__ __launch_bounds__(256, 6) void convs(
    const u16* __restrict__ hA, const u16* __restrict__ gA,
    const u16* __restrict__ BtW, const u16* __restrict__ BtG,
    const float* __restrict__ bias,
    u16* __restrict__ outB, u16* __restrict__ outB8)
{
    constexpr int K = 128, P = 72;
    __shared__ __align__(16) char smem[18432];
    u16* bl = (u16*)smem;
    const int wave = threadIdx.x >> 6, lane = threadIdx.x & 63;
    const int m = lane & 15, q = lane >> 4;
    const int nh = wave >> 1;
    const int rowbase = blockIdx.x * 32 + (wave & 1) * 16;
    const int row = rowbase + m;
    const bool rok = row < NNODE;
    const short8 z8 = {0,0,0,0,0,0,0,0};

    short8 af1[4], af2[4];
    {
        const short8* ap1 = (const short8*)(hA + (long long)row * K);
        const short8* ap2 = (const short8*)(gA + (long long)row * K);
        #pragma unroll
        for (int k = 0; k < 4; ++k) {
            af1[k] = rok ? ap1[k * 4 + q] : z8;
            af2[k] = rok ? ap2[k * 4 + q] : z8;
        }
    }

    f32x4 acc[4];
    #pragma unroll
    for (int j = 0; j < 4; ++j) acc[j] = (f32x4){0.f,0.f,0.f,0.f};

    #pragma unroll
    for (int ph = 0; ph < 4; ++ph) {             // {W,G} x {K-chunk 0,1}
        const int pass = ph >> 1, ch = ph & 1;
        const u16* Bsrc = pass ? BtG : BtW;
        if (ph) __syncthreads();
        for (int t = threadIdx.x; t < 1024; t += 256) {   // 128 rows x 64 cols bf16
            int r = t >> 3, c = t & 7;
            *(short8*)&bl[r * P + c * 8] =
                *(const short8*)&Bsrc[(long long)r * K + ch*64 + c*8];
        }
        __syncthreads();
        #pragma unroll
        for (int j = 0; j < 4; ++j)
            #pragma unroll
            for (int kk = 0; kk < 2; ++kk) {
                short8 b_ = *(const short8*)&bl[(nh*64 + j*16 + m) * P + kk*32 + q*8];
                acc[j] = __builtin_amdgcn_mfma_f32_16x16x32_bf16(
                    pass ? af2[2*ch + kk] : af1[2*ch + kk], b_, acc[j], 0, 0, 0);
            }
    }

    __syncthreads();
    float* accW = (float*)smem + wave * 16 * 65;
    #pragma unroll
    for (int j = 0; j < 4; ++j)
        #pragma unroll
        for (int r = 0; r < 4; ++r)
            accW[(q*4 + r) * 65 + j*16 + m] = acc[j][r];

    const int hw = lane >> 5;
    const int c0 = (lane & 31) * 2;
    float2 bv = {bias[nh*64 + c0], bias[nh*64 + c0 + 1]};
    #pragma unroll
    for (int rl8 = 0; rl8 < 8; ++rl8) {
        int rl = hw * 8 + rl8;
        int rowD = rowbase + rl;
        if (rowD >= NNODE) continue;
        float2 v = *(const float2*)&accW[rl * 65 + c0];
        long long o = (long long)rowD * 128 + nh*64 + c0;
        ushort2 hh = *(const ushort2*)&hA[o];
        float n0 = bf2f(hh.x) + EPSC * ftanh(v.x + bv.x);
        float n1 = bf2f(hh.y) + EPSC * ftanh(v.y + bv.y);
        ushort2 ob; ob.x = f2bf(n0); ob.y = f2bf(n1);
        *(ushort2*)&outB[o] = ob;
        outB8[o >> 1] = pk_fp8(n0, n1);
    }
}

// ---- conv step iter3 (full-width) + fused h2 = leaky(leaky(h_new)@w2^T+b2) ----
__global__ __launch_bounds__(256, 4) void convt(
    const u16* __restrict__ hA, const u16* __restrict__ gA,
    const u16* __restrict__ BtW, const u16* __restrict__ BtG,
    const float* __restrict__ bias,
    u16* __restrict__ outB, u16* __restrict__ outB8,
    const float* __restrict__ w2f, const float* __restrict__ b2)
{
    constexpr int K = 128, P = 72, CW = 129, PH = 136;
    __shared__ __align__(16) char smem[18432];
    u16*   bl   = (u16*)smem;
    float* accL = (float*)smem;
    const int wave = threadIdx.x >> 6, lane = threadIdx.x & 63;
    const int m = lane & 15, q = lane >> 4;
    const int rowbase = blockIdx.x * 64 + wave * 16;
    const int row = rowbase + m;
    const bool rok = row < NNODE;
    const short8 z8 = {0,0,0,0,0,0,0,0};

    short8 af1[4], af2[4];
    {
        const short8* ap1 = (const short8*)(hA + (long long)row * K);
        const short8* ap2 = (const short8*)(gA + (long long)row * K);
        #pragma unroll
        for (int k = 0; k < 4; ++k) {
            af1[k] = rok ? ap1[k * 4 + q] : z8;
            af2[k] = rok ? ap2[k * 4 + q] : z8;
        }
    }

    f32x4 acc[8];
    #pragma unroll
    for (int j = 0; j < 8; ++j) acc[j] = (f32x4){0.f,0.f,0.f,0.f};

    #pragma unroll
    for (int ph = 0; ph < 4; ++ph) {               // {W,G} x {K-chunk 0,1}, full 128 rows
        const int pass = ph >> 1, ch = ph & 1;
        const u16* Bsrc = pass ? BtG : BtW;
        if (ph) __syncthreads();
        for (int t = threadIdx.x; t < 1024; t += 256) {
            int r = t >> 3, c = t & 7;
            *(short8*)&bl[r * P + c * 8] =
                *(const short8*)&Bsrc[(long long)r * K + ch*64 + c*8];
        }
        __syncthreads();
        #pragma unroll
        for (int j = 0; j < 8; ++j)
            #pragma unroll
            for (int kk = 0; kk < 2; ++kk) {
                short8 b_ = *(const short8*)&bl[(j*16 + m) * P + kk*32 + q*8];
                acc[j] = __builtin_amdgcn_mfma_f32_16x16x32_bf16(
                    pass ? af2[2*ch + kk] : af1[2*ch + kk], b_, acc[j], 0, 0, 0);
            }
    }

    // h_new = h + eps*tanh(acc+b), leaky -> hv regs (2-pass accL, 32x129 f32)
    const int c0 = lane * 2;
    u32 hv[16];
    {
        float2 bv = {bias[c0], bias[c0 + 1]};
        #pragma unroll
        for (int p = 0; p < 2; ++p) {
            __syncthreads();
            if ((wave >> 1) == p) {
                int lr = (wave & 1) * 16;
                #pragma unroll
                for (int j = 0; j < 8; ++j)
                    #pragma unroll
                    for (int r = 0; r < 4; ++r)
                        accL[(lr + q*4 + r) * CW + j*16 + m] = acc[j][r];
            }
            __syncthreads();
            if ((wave >> 1) == p) {
                int lr = (wave & 1) * 16;
                #pragma unroll
                for (int rl = 0; rl < 16; ++rl) {
                    int rowD = rowbase + rl;
                    float n0 = 0.f, n1 = 0.f;
                    if (rowD < NNODE) {
                        float2 v = *(const float2*)&accL[(lr + rl) * CW + c0];
                        long long o = (long long)rowD * K + c0;
                        ushort2 hh = *(const ushort2*)&hA[o];
                        n0 = bf2f(hh.x) + EPSC * ftanh(v.x + bv.x);
                        n1 = bf2f(hh.y) + EPSC * ftanh(v.y + bv.y);
                        n0 = n0 > 0.f ? n0 : 0.01f * n0;
                        n1 = n1 > 0.f ? n1 : 0.01f * n1;
                    }
                    hv[rl] = (u32)f2bf(n0) | ((u32)f2bf(n1) << 16);
                }
            }
        }
    }

    // h_new tile -> LDS [64][136] bf16, read A-frags
    __syncthreads();
    #pragma unroll
    for (int rl = 0; rl < 16; ++rl)
        *(u32*)&bl[(wave*16 + rl) * PH + c0] = hv[rl];
    __syncthreads();
    short8 af3[4];
    #pragma unroll
    for (int k = 0; k < 4; ++k)
        af3[k] = *(const short8*)&bl[(wave*16 + m) * PH + k*32 + q*8];

    // h2 GEMM: w2 [64][128] f32 on-the-fly, 2 K-chunks
    f32x4 acc2[4];
    #pragma unroll
    for (int j = 0; j < 4; ++j) acc2[j] = (f32x4){0.f,0.f,0.f,0.f};
    #pragma unroll
    for (int ch = 0; ch < 2; ++ch) {
        __syncthreads();
        for (int t = threadIdx.x; t < 512; t += 256) {
            int r = t >> 3, c = t & 7;
            const float4* pw = (const float4*)&w2f[(long long)r * K + ch*64 + c*8];
            *(short8*)&bl[r * P + c * 8] = cvt8(pw[0], pw[1]);
        }
        __syncthreads();
        #pragma unroll
        for (int j = 0; j < 4; ++j)
            #pragma unroll
            for (int kk = 0; kk < 2; ++kk) {
                short8 b_ = *(const short8*)&bl[(j*16 + m) * P + kk*32 + q*8];
                acc2[j] = __builtin_amdgcn_mfma_f32_16x16x32_bf16(af3[2*ch + kk], b_, acc2[j], 0, 0, 0);
            }
    }

    // h2 epilogue (2-pass, 32x65 f32), leaky, store
    constexpr int CW2 = 65;
    const int hw = lane >> 5;
    const int c2 = (lane & 31) * 2;
    float2 bv2 = {b2[c2], b2[c2 + 1]};
    #pragma unroll
    for (int p = 0; p < 2; ++p) {
        __syncthreads();
        if ((wave >> 1) == p) {
            int lr = (wave & 1) * 16;
            #pragma unroll
            for (int j = 0; j < 4; ++j)
                #pragma unroll
                for (int r = 0; r < 4; ++r)
                    accL[(lr + q*4 + r) * CW2 + j*16 + m] = acc2[j][r];
        }
        __syncthreads();
        if ((wave >> 1) == p) {
            int lr = (wave & 1) * 16;
            #pragma unroll
            for (int rl8 = 0; rl8 < 8; ++rl8) {
                int rl = hw * 8 + rl8;
                int rowD = rowbase + rl;
                if (rowD >= NNODE) continue;
                float2 v = *(const float2*)&accL[(lr + rl) * CW2 + c2];
                v.x += bv2.x; v.y += bv2.y;
                v.x = v.x > 0.f ? v.x : 0.01f * v.x;
                v.y = v.y > 0.f ? v.y : 0.01f * v.y;
                long long o = (long long)rowD * 64 + c2;
                ushort2 ob; ob.x = f2bf(v.x); ob.y = f2bf(v.y);
                *(ushort2*)&outB[o] = ob;
                outB8[o >> 1] = pk_fp8(v.x, v.y);
            }
        }
    }
}

// ---- fused conv2 + FC + log_softmax ----
__global__ __launch_bounds__(256, 4) void conv2fc(
    const u16* __restrict__ hA,      // h2 [M,64] bf16
    const u16* __restrict__ gA,      // Ah2 [M,64] bf16
    const u16* __restrict__ BtW, const u16* __restrict__ BtG,
    const float* __restrict__ bias,
    const float* __restrict__ wfc, const float* __restrict__ bfc,
    float* __restrict__ outF)
{
    constexpr int K = 64, NT = 4, KS = 2, P = 72, CW = 65;
    constexpr int R1 = 64 * CW * 4;    // 16640
    __shared__ __align__(16) char smem[R1 + 64 * P * 2];
    u16*   bl   = (u16*)smem;
    float* accL = (float*)smem;
    u16*   aggT = (u16*)(smem + R1);
    const int wave = threadIdx.x >> 6, lane = threadIdx.x & 63;
    const int m = lane & 15, q = lane >> 4;
    const int rowbase = blockIdx.x * 64 + wave * 16;
    const int row = rowbase + m;
    const bool rok = row < NNODE;
    const short8 z8 = {0,0,0,0,0,0,0,0};

    short8 af1[KS], af2[KS];
    {
        const short8* ap1 = (const short8*)(hA + (long long)row * K);
        const short8* ap2 = (const short8*)(gA + (long long)row * K);
        #pragma unroll
        for (int k = 0; k < KS; ++k) {
            af1[k] = rok ? ap1[k * 4 + q] : z8;
            af2[k] = rok ? ap2[k * 4 + q] : z8;
        }
    }

    f32x4 acc[NT];
    #pragma unroll
    for (int j = 0; j < NT; ++j) acc[j] = (f32x4){0.f,0.f,0.f,0.f};

    #pragma unroll
    for (int pass = 0; pass < 2; ++pass) {
        const u16* Bcur = pass ? BtG : BtW;
        if (pass) __syncthreads();
        for (int t = threadIdx.x; t < 512; t += 256) {
            int r = t >> 3, c = t & 7;
            *(short8*)&bl[r * P + c * 8] = *(const short8*)&Bcur[(long long)r * K + c * 8];
        }
        __syncthreads();
        #pragma unroll
        for (int j = 0; j < NT; ++j)
            #pragma unroll
            for (int k = 0; k < KS; ++k) {
                short8 b_ = *(const short8*)&bl[(j*16 + m) * P + k*32 + q*8];
                acc[j] = __builtin_amdgcn_mfma_f32_16x16x32_bf16(
                    pass ? af2[k] : af1[k], b_, acc[j], 0, 0, 0);
            }
    }

    __syncthreads();
    #pragma unroll
    for (int j = 0; j < NT; ++j)
        #pragma unroll
        for (int r = 0; r < 4; ++r)
            accL[(wave*16 + q*4 + r) * CW + j*16 + m] = acc[j][r];
    __syncthreads();

    // h2n = h2 + eps*tanh(acc + b_a2) -> aggT tile
    {
        const int c0 = lane * 2;
        if (c0 < 64) {
            float2 bv = {bias[c0], bias[c0 + 1]};
            #pragma unroll
            for (int rl = 0; rl < 16; ++rl) {
                int rowD = rowbase + rl;
                float n0 = 0.f, n1 = 0.f;
                if (rowD < NNODE) {
                    float2 v = *(const float2*)&accL[(wave*16 + rl) * CW + c0];
                    long long o = (long long)rowD * 64 + c0;
                    ushort2 hh = *(const ushort2*)&hA[o];
                    n0 = bf2f(hh.x) + EPSC * ftanh(v.x + bv.x);
                    n1 = bf2f(hh.y) + EPSC * ftanh(v.y + bv.y);
                }
                ushort2 ob; ob.x = f2bf(n0); ob.y = f2bf(n1);
                *(ushort2*)&aggT[(wave*16 + rl) * P + c0] = ob;
            }
        }
    }
    __syncthreads();

    short8 af4[KS];
    #pragma unroll
    for (int k = 0; k < KS; ++k)
        af4[k] = *(const short8*)&aggT[(wave*16 + m) * P + k*32 + q*8];

    // stage wfc [40,64] f32 -> bf16 on the fly, zero-pad to 48 rows
    for (int t = threadIdx.x; t < 384; t += 256) {
        int r = t >> 3, c = t & 7;
        short8 v = z8;
        if (r < 40) {
            const float4* pw = (const float4*)&wfc[(long long)r * K + c * 8];
            v = cvt8(pw[0], pw[1]);
        }
        *(short8*)&bl[r * P + c * 8] = v;
    }
    __syncthreads();

    f32x4 acc3[3];
    #pragma unroll
    for (int j = 0; j < 3; ++j) acc3[j] = (f32x4){0.f,0.f,0.f,0.f};
    #pragma unroll
    for (int j = 0; j < 3; ++j)
        #pragma unroll
        for (int k = 0; k < KS; ++k) {
            short8 b_ = *(const short8*)&bl[(j*16 + m) * P + k*32 + q*8];
            acc3[j] = __builtin_amdgcn_mfma_f32_16x16x32_bf16(af4[k], b_, acc3[j], 0, 0, 0);
        }

    __syncthreads();
    constexpr int CW3 = 49;
    #pragma unroll
    for (int j = 0; j < 3; ++j)
        #pragma unroll
        for (int r = 0; r < 4; ++r)
            accL[(wave*16 + q*4 + r) * CW3 + j*16 + m] = acc3[j][r];
    __syncthreads();

    float mrow = 0.f, lrow = 0.f;
    if (lane < 16) {
        const float* rp = &accL[(wave*16 + lane) * CW3];
        float mx = -1e30f;
        for (int c = 0; c < 40; ++c) mx = fmaxf(mx, rp[c] + bfc[c]);
        float s = 0.f;
        for (int c = 0; c < 40; ++c) s += expf(rp[c] + bfc[c] - mx);
        mrow = mx; lrow = logf(s);
    }
    for (int rl = 0; rl < 16; ++rl) {
        float mm = __shfl(mrow, rl);
        float ll = __shfl(lrow, rl);
        int rowD = rowbase + rl;
        if (rowD < NNODE && lane < 40) {
            float v = accL[(wave*16 + rl) * CW3 + lane] + bfc[lane];
            outF[(long long)rowD * 40 + lane] = v - mm - ll;
        }
    }
}

extern "C" void kernel_launch(void* const* d_in, const int* in_sizes, int n_in,
                              void* d_out, int out_size, void* d_ws, size_t ws_size,
                              hipStream_t stream) {
    const float* x     = (const float*)d_in[0];
    const int*   ei    = (const int*)d_in[1];
    const float* w_hid = (const float*)d_in[2];
    const float* b_hid = (const float*)d_in[3];
    const float* W_a1  = (const float*)d_in[4];
    const float* gcn1  = (const float*)d_in[5];
    const float* b_a1  = (const float*)d_in[6];
    const float* w2    = (const float*)d_in[7];
    const float* b2    = (const float*)d_in[8];
    const float* W_a2  = (const float*)d_in[9];
    const float* gcn2  = (const float*)d_in[10];
    const float* b_a2  = (const float*)d_in[11];
    const float* wfc   = (const float*)d_in[12];
    const float* bfc   = (const float*)d_in[13];
    float* ws = (float*)d_ws;
    float* out = (float*)d_out;

    float* dinv   = ws + O_DINV;
    int*   degi   = (int*)(ws + O_DEGI);
    int*   gcur   = (int*)(ws + O_GCUR);
    int*   rowptr = (int*)(ws + O_ROWPTR);
    int*   cursor = (int*)(ws + O_CURSOR);
    int2*  ecsr   = (int2*)(ws + O_ECSR);
    u16* g1tB = (u16*)(ws + O_G1TB);
    u16* aw1B = (u16*)(ws + O_AW1B);
    u16* aw2B = (u16*)(ws + O_AW2B);
    u16* g2tB = (u16*)(ws + O_G2TB);
    u16* aggB = (u16*)(ws + O_AGGB);
    u16* hB0  = (u16*)(ws + O_HB0);
    u16* hB1  = (u16*)(ws + O_HB1);
    u16* s0   = (u16*)(ws + O_S0);
    u16* s1   = (u16*)(ws + O_S1);

    // zero degi (50000 ints) + gcur (adjacent) in one async fill
    hipMemsetAsync((char*)d_ws + (size_t)O_DEGI * 4, 0, (NNODE + 1) * 4, stream);

    // x-GEMM (32-row blocks) + concurrent deg-count + weight-prep roles
    xgemm<<<NT32 + XDEG + XW, 256, 0, stream>>>(
        x, w_hid, b_hid, hB0, s0, ei, degi, W_a1, gcn1, W_a2, gcn2, ws);

    const int nNodeB = (NNODE + 255) / 256;
    alloc_kernel<<<nNodeB, 256, 0, stream>>>(degi, dinv, rowptr, cursor, gcur);
    fill_kernel<<<(NEDGE + 255) / 256, 256, 0, stream>>>(ei, dinv, cursor, ecsr);

    const int gatherBlocks = (NNODE * 64 + 255) / 256;   // 12500

    // conv1 iter1
    gather_kernel<128><<<gatherBlocks, 256, 0, stream>>>(
        rowptr, degi, ecsr, dinv, (const u32*)s0, aggB);
    convs<<<NT32, 256, 0, stream>>>(hB0, aggB, aw1B, g1tB, b_a1, hB1, s1);
    // conv1 iter2
    gather_kernel<128><<<gatherBlocks, 256, 0, stream>>>(
        rowptr, degi, ecsr, dinv, (const u32*)s1, aggB);
    convs<<<NT32, 256, 0, stream>>>(hB1, aggB, aw1B, g1tB, b_a1, hB0, s0);
    // conv1 iter3 + fused h2 GEMM (full-width)
    gather_kernel<128><<<gatherBlocks, 256, 0, stream>>>(
        rowptr, degi, ecsr, dinv, (const u32*)s0, aggB);
    convt<<<NTILE, 256, 0, stream>>>(hB0, aggB, aw1B, g1tB, b_a1, hB1, s1, w2, b2);

    // conv2 + fc + log_softmax
    gather_kernel<64><<<gatherBlocks, 256, 0, stream>>>(
        rowptr, degi, ecsr, dinv, (const u32*)s1, aggB);
    conv2fc<<<NTILE, 256, 0, stream>>>(hB1, aggB, aw2B, g2tB, b_a2, wfc, bfc, out);
}